// Round 1
// baseline (2464.894 us; speedup 1.0000x reference)
//
#include <hip/hip_runtime.h>
#include <hip/hip_bf16.h>

// ---------------------------------------------------------------------------
// SeqAttention (AlphaFold-style gated MHA with pair bias) on MI355X/gfx950.
// B=2, N=1024, C_IN=512, H=16, D=32 (H*D=512), C_Z=128.
//
// Pipeline:
//   K1 ln_m    : LayerNorm(m) -> mln                                [2048,512]
//   K2 gemm512 : Q=mln@wq*sc, K=mln@wk, V=mln@wv, G=sigmoid(mln@wg+bg)
//   K3 zbias   : LN(z)@ (wz*ln_z_w) + ln_z_b@wz  -> bias bf16 [b][h][q][k]
//                (memory-bound: 1.07 GB z read; bf16 MFMA for the einsum)
//   K4 attn    : scores=QK^T+mask_bias+pair_bias; softmax; O=P@V
//   K5 gemm512 : out = (O .* G) @ w_o + b_o
//
// Workspace layout (floats): mln@0, q@1M, k@2M, v@3M, g@4M, o@5M,
// bias bf16 @6M (33.5M bf16 = 64 MiB). Total 88 MiB of d_ws.
// ---------------------------------------------------------------------------

#define B_   2
#define N_   1024
#define CIN  512
#define H_   16
#define D_   32
#define CZ   128
#define INFV 1e9f
#define EPS_ 1e-5f
#define QSCALE 0.17677669529663687f  // 32^-0.5

typedef __bf16 bf16_t;
typedef __bf16 bf16x8 __attribute__((ext_vector_type(8)));
typedef __bf16 bf16x4 __attribute__((ext_vector_type(4)));
typedef float  f32x4  __attribute__((ext_vector_type(4)));

static __device__ __forceinline__ float dot4(const float4 a, const float4 b) {
  return a.x * b.x + a.y * b.y + a.z * b.z + a.w * b.w;
}

// --------------------------------------------------------------- K1: LN(m)
__global__ __launch_bounds__(128) void ln_m_kernel(
    const float* __restrict__ m, const float* __restrict__ w,
    const float* __restrict__ b, float* __restrict__ out) {
  const int row = blockIdx.x;
  const int t = threadIdx.x;
  const float4 x = *(const float4*)(m + (size_t)row * CIN + t * 4);
  float s = x.x + x.y + x.z + x.w;
  float ss = dot4(x, x);
#pragma unroll
  for (int off = 32; off >= 1; off >>= 1) {
    s += __shfl_xor(s, off);
    ss += __shfl_xor(ss, off);
  }
  __shared__ float sm[2][2];
  const int wv = t >> 6;
  if ((t & 63) == 0) { sm[0][wv] = s; sm[1][wv] = ss; }
  __syncthreads();
  const float S = sm[0][0] + sm[0][1];
  const float SS = sm[1][0] + sm[1][1];
  const float mu = S * (1.0f / CIN);
  const float var = SS * (1.0f / CIN) - mu * mu;
  const float rs = rsqrtf(var + EPS_);
  const float4 w4 = *(const float4*)(w + t * 4);
  const float4 b4 = *(const float4*)(b + t * 4);
  float4 o;
  o.x = (x.x - mu) * rs * w4.x + b4.x;
  o.y = (x.y - mu) * rs * w4.y + b4.y;
  o.z = (x.z - mu) * rs * w4.z + b4.z;
  o.w = (x.w - mu) * rs * w4.w + b4.w;
  *(float4*)(out + (size_t)row * CIN + t * 4) = o;
}

// ------------------------------------------- K2/K5: fp32 tiled 512-K GEMM
// C[2048,512] = A[2048,512] (optionally .*A2) @ W[512,512], epilogue by mode:
// 0: *QSCALE (q)   1: none (k)   2: none (v)   3: sigmoid(x+bg) (g)
// 4: x+bo -> final output
__global__ __launch_bounds__(256) void gemm512(
    const float* __restrict__ A, const float* __restrict__ A2,
    const float* __restrict__ W0, const float* __restrict__ W1,
    const float* __restrict__ W2, const float* __restrict__ W3,
    const float* __restrict__ bg, const float* __restrict__ bo,
    float* __restrict__ O0, float* __restrict__ O1, float* __restrict__ O2,
    float* __restrict__ O3, int kind) {
  const int mode = (kind >= 0) ? kind : (int)blockIdx.z;
  const float* W = (mode == 0 || mode == 4) ? W0
                   : (mode == 1)            ? W1
                   : (mode == 2)            ? W2
                                            : W3;
  float* O = (mode == 0 || mode == 4) ? O0
             : (mode == 1)            ? O1
             : (mode == 2)            ? O2
                                      : O3;
  const int t = threadIdx.x;
  const int tx = t & 15, ty = t >> 4;
  const int row0 = blockIdx.y * 64, col0 = blockIdx.x * 64;
  __shared__ __align__(16) float As[16 * 68];  // [k][row], pad 68
  __shared__ __align__(16) float Bs[16 * 68];  // [k][col], pad 68
  float acc[4][4] = {};
  const int ar = t >> 2, ak = t & 3;   // A stage: row ar, float4 ak of k
  const int bk = t >> 4, bc = t & 15;  // B stage: k bk, float4 bc of col

  for (int k0 = 0; k0 < 512; k0 += 16) {
    __syncthreads();
    float4 a4 = *(const float4*)(A + (size_t)(row0 + ar) * 512 + k0 + ak * 4);
    if (A2) {
      const float4 g4 =
          *(const float4*)(A2 + (size_t)(row0 + ar) * 512 + k0 + ak * 4);
      a4.x *= g4.x; a4.y *= g4.y; a4.z *= g4.z; a4.w *= g4.w;
    }
    As[(ak * 4 + 0) * 68 + ar] = a4.x;
    As[(ak * 4 + 1) * 68 + ar] = a4.y;
    As[(ak * 4 + 2) * 68 + ar] = a4.z;
    As[(ak * 4 + 3) * 68 + ar] = a4.w;
    const float4 b4 =
        *(const float4*)(W + (size_t)(k0 + bk) * 512 + col0 + bc * 4);
    *(float4*)&Bs[bk * 68 + bc * 4] = b4;
    __syncthreads();
#pragma unroll
    for (int kk = 0; kk < 16; ++kk) {
      const float4 av = *(const float4*)&As[kk * 68 + ty * 4];
      const float4 bv = *(const float4*)&Bs[kk * 68 + tx * 4];
      acc[0][0] += av.x * bv.x; acc[0][1] += av.x * bv.y;
      acc[0][2] += av.x * bv.z; acc[0][3] += av.x * bv.w;
      acc[1][0] += av.y * bv.x; acc[1][1] += av.y * bv.y;
      acc[1][2] += av.y * bv.z; acc[1][3] += av.y * bv.w;
      acc[2][0] += av.z * bv.x; acc[2][1] += av.z * bv.y;
      acc[2][2] += av.z * bv.z; acc[2][3] += av.z * bv.w;
      acc[3][0] += av.w * bv.x; acc[3][1] += av.w * bv.y;
      acc[3][2] += av.w * bv.z; acc[3][3] += av.w * bv.w;
    }
  }
#pragma unroll
  for (int i = 0; i < 4; ++i) {
    const int row = row0 + ty * 4 + i;
    const int col = col0 + tx * 4;
    float4 r;
    r.x = acc[i][0]; r.y = acc[i][1]; r.z = acc[i][2]; r.w = acc[i][3];
    if (mode == 0) {
      r.x *= QSCALE; r.y *= QSCALE; r.z *= QSCALE; r.w *= QSCALE;
    } else if (mode == 3) {
      r.x = 1.0f / (1.0f + __expf(-(r.x + bg[col + 0])));
      r.y = 1.0f / (1.0f + __expf(-(r.y + bg[col + 1])));
      r.z = 1.0f / (1.0f + __expf(-(r.z + bg[col + 2])));
      r.w = 1.0f / (1.0f + __expf(-(r.w + bg[col + 3])));
    } else if (mode == 4) {
      r.x += bo[col + 0]; r.y += bo[col + 1];
      r.z += bo[col + 2]; r.w += bo[col + 3];
    }
    *(float4*)(O + (size_t)row * 512 + col) = r;
  }
}

// ------------------------------------- K3: LN(z) @ wz' -> bias bf16 [b][h][q][k]
// One block per (b, q-row). 16 superpasses x 64 k-rows.
// bias[h] = sum_c xhat_c*(ln_z_w[c]*wz[c][h]) + sum_c ln_z_b[c]*wz[c][h]
__global__ __launch_bounds__(256) void zbias_kernel(
    const float* __restrict__ z, const float* __restrict__ lnzw,
    const float* __restrict__ lnzb, const float* __restrict__ wz,
    bf16_t* __restrict__ biasws) {
  const int qrow = blockIdx.x, b = blockIdx.y;
  const int t = threadIdx.x;
  const int lane = t & 63, wv = t >> 6;
  const int h = lane & 15, quad = lane >> 4;

  // B fragments: wzf[cc][j] = bf16(wz[k][h]*ln_z_w[k]), k = cc*32+quad*8+j
  bf16x8 wzf[4];
#pragma unroll
  for (int cc = 0; cc < 4; ++cc) {
#pragma unroll
    for (int j = 0; j < 8; ++j) {
      const int kch = cc * 32 + quad * 8 + j;
      wzf[cc][j] = (bf16_t)(wz[kch * 16 + h] * lnzw[kch]);
    }
  }
  float b0 = 0.0f;  // bias offset from LN beta
  for (int c = 0; c < 128; ++c) b0 += lnzb[c] * wz[c * 16 + h];

  __shared__ __align__(16) bf16_t znL[64 * 136];  // pad 136 breaks banks
  __shared__ __align__(16) bf16_t btL[16 * 68];   // bias transpose tile

  const int r = t >> 2, i4 = t & 3;  // 4 lanes per (q,k) row, 32 ch each
  const size_t zrow0 = (size_t)(b * N_ + qrow) * N_;

  for (int sp = 0; sp < 16; ++sp) {
    // ---- A: load 64 z-rows coalesced, LN in registers --------------------
    const float* zp = z + (zrow0 + sp * 64 + r) * CZ + i4 * 4;
    float4 zx[8];
#pragma unroll
    for (int s = 0; s < 8; ++s) zx[s] = *(const float4*)(zp + s * 16);
    float sm = 0.f, sq = 0.f;
#pragma unroll
    for (int s = 0; s < 8; ++s) {
      sm += zx[s].x + zx[s].y + zx[s].z + zx[s].w;
      sq += dot4(zx[s], zx[s]);
    }
    sm += __shfl_xor(sm, 1); sq += __shfl_xor(sq, 1);
    sm += __shfl_xor(sm, 2); sq += __shfl_xor(sq, 2);
    const float mu = sm * (1.0f / 128.0f);
    const float var = sq * (1.0f / 128.0f) - mu * mu;
    const float rs = rsqrtf(var + EPS_);
#pragma unroll
    for (int s = 0; s < 8; ++s) {
      bf16x4 v;
      v[0] = (bf16_t)((zx[s].x - mu) * rs);
      v[1] = (bf16_t)((zx[s].y - mu) * rs);
      v[2] = (bf16_t)((zx[s].z - mu) * rs);
      v[3] = (bf16_t)((zx[s].w - mu) * rs);
      *(bf16x4*)&znL[r * 136 + s * 16 + i4 * 4] = v;
    }
    __syncthreads();
    // ---- B: per-wave MFMA over its 16-row sub-tile -----------------------
    {
      const int wbase = wv * 16;
      const int arow = wbase + (lane & 15);
      f32x4 acc = {b0, b0, b0, b0};
#pragma unroll
      for (int cc = 0; cc < 4; ++cc) {
        const bf16x8 af =
            *(const bf16x8*)&znL[arow * 136 + cc * 32 + quad * 8];
        acc = __builtin_amdgcn_mfma_f32_16x16x32_bf16(af, wzf[cc], acc, 0, 0, 0);
      }
      bf16x4 bt;
      bt[0] = (bf16_t)acc[0]; bt[1] = (bf16_t)acc[1];
      bt[2] = (bf16_t)acc[2]; bt[3] = (bf16_t)acc[3];
      // D layout: col = lane&15 (=h), row = quad*4+reg (k within sub-tile)
      *(bf16x4*)&btL[h * 68 + wbase + quad * 4] = bt;
    }
    __syncthreads();
    // ---- C: coalesced bf16 store of the 16h x 64k tile -------------------
    {
      const int hh = t >> 4, kq = t & 15;
      const bf16x4 v = *(const bf16x4*)&btL[hh * 68 + kq * 4];
      *(bf16x4*)(biasws + ((size_t)(b * H_ + hh) * N_ + qrow) * N_ + sp * 64 +
                 kq * 4) = v;
    }
    // no barrier needed here: next A writes znL (B-reads completed before
    // sync2); next B writes btL only after next sync1 (C-reads done by then)
  }
}

// ----------------------------------------------- K4: attention per (b,h,8q)
__global__ __launch_bounds__(256) void attn_kernel(
    const float* __restrict__ qws, const float* __restrict__ kws,
    const float* __restrict__ vws, const bf16_t* __restrict__ biasws,
    const float* __restrict__ mask, float* __restrict__ ows) {
  const int qt = blockIdx.x, h = blockIdx.y, b = blockIdx.z;
  const int t = threadIdx.x;
  __shared__ __align__(16) float sb[8448];  // scores [8][1032] / oL [256][33]
  __shared__ __align__(16) float qsL[256];  // q tile [8][32]
  __shared__ float linvL[8];
  {
    const int qr = t >> 5, d = t & 31;
    qsL[qr * 32 + d] =
        qws[(size_t)(b * N_ + qt * 8 + qr) * 512 + h * 32 + d];
  }
  __syncthreads();
  // ---- P1: scores = q.k + mask_bias + pair_bias -------------------------
  const size_t bb = ((size_t)(b * H_ + h) * N_ + qt * 8) * N_;
#pragma unroll 1
  for (int ch = 0; ch < 4; ++ch) {
    const int kk = ch * 256 + t;
    const float* kp = kws + (size_t)(b * N_ + kk) * 512 + h * 32;
    float4 kr[8];
#pragma unroll
    for (int s = 0; s < 8; ++s) kr[s] = *(const float4*)(kp + s * 4);
    const float mb = INFV * (mask[b * N_ + kk] - 1.0f);
#pragma unroll
    for (int q = 0; q < 8; ++q) {
      float s = 0.f;
#pragma unroll
      for (int s4 = 0; s4 < 8; ++s4) {
        const float4 qv = *(const float4*)&qsL[q * 32 + s4 * 4];
        s += dot4(qv, kr[s4]);
      }
      s += mb + (float)biasws[bb + (size_t)q * N_ + kk];
      sb[q * 1032 + kk] = s;
    }
  }
  __syncthreads();
  // ---- P2: softmax (wave per 2 rows, unnormalized p stored, 1/l saved) ---
  {
    const int wv = t >> 6, lane = t & 63;
#pragma unroll 1
    for (int rr = 0; rr < 2; ++rr) {
      const int row = wv + rr * 4;
      float v[16];
      float mx = -3.4e38f;
#pragma unroll
      for (int mm = 0; mm < 16; ++mm) {
        v[mm] = sb[row * 1032 + lane + mm * 64];
        mx = fmaxf(mx, v[mm]);
      }
#pragma unroll
      for (int off = 1; off <= 32; off <<= 1) mx = fmaxf(mx, __shfl_xor(mx, off));
      float sum = 0.f;
#pragma unroll
      for (int mm = 0; mm < 16; ++mm) {
        v[mm] = __expf(v[mm] - mx);
        sum += v[mm];
        sb[row * 1032 + lane + mm * 64] = v[mm];
      }
#pragma unroll
      for (int off = 1; off <= 32; off <<= 1) sum += __shfl_xor(sum, off);
      if (lane == 0) linvL[row] = 1.0f / sum;
    }
  }
  __syncthreads();
  // ---- P3: O = P @ V (thread = (q, k-strip), transpose-reduce via LDS) ---
  const int q = t >> 5, ks = t & 31;
  float op[32];
#pragma unroll
  for (int d = 0; d < 32; ++d) op[d] = 0.f;
#pragma unroll 1
  for (int mm = 0; mm < 32; ++mm) {
    const int k = mm * 32 + ks;
    const float p = sb[q * 1032 + k];
    const float* vp = vws + (size_t)(b * N_ + k) * 512 + h * 32;
#pragma unroll
    for (int s4 = 0; s4 < 8; ++s4) {
      const float4 vv = *(const float4*)(vp + s4 * 4);
      op[s4 * 4 + 0] += p * vv.x;
      op[s4 * 4 + 1] += p * vv.y;
      op[s4 * 4 + 2] += p * vv.z;
      op[s4 * 4 + 3] += p * vv.w;
    }
  }
  __syncthreads();  // all p-reads of sb done before overwrite
#pragma unroll
  for (int d = 0; d < 32; ++d) sb[(q * 32 + d) * 33 + ks] = op[d];
  __syncthreads();
  {
    const int d = t & 31;
    float s = 0.f;
#pragma unroll
    for (int k2 = 0; k2 < 32; ++k2) s += sb[(q * 32 + d) * 33 + k2];
    s *= linvL[q];
    ows[(size_t)(b * N_ + qt * 8 + q) * 512 + h * 32 + d] = s;
  }
}

// ---------------------------------------------------------------------------
extern "C" void kernel_launch(void* const* d_in, const int* in_sizes, int n_in,
                              void* d_out, int out_size, void* d_ws,
                              size_t ws_size, hipStream_t stream) {
  (void)in_sizes; (void)n_in; (void)out_size; (void)ws_size;
  const float* m    = (const float*)d_in[0];
  const float* z    = (const float*)d_in[1];
  const float* mask = (const float*)d_in[2];
  const float* lnmw = (const float*)d_in[3];
  const float* lnmb = (const float*)d_in[4];
  const float* lnzw = (const float*)d_in[5];
  const float* lnzb = (const float*)d_in[6];
  const float* wz   = (const float*)d_in[7];
  const float* wq   = (const float*)d_in[8];
  const float* wk   = (const float*)d_in[9];
  const float* wvv  = (const float*)d_in[10];
  const float* wg   = (const float*)d_in[11];
  const float* bg   = (const float*)d_in[12];
  const float* wo   = (const float*)d_in[13];
  const float* bo   = (const float*)d_in[14];
  float* out = (float*)d_out;

  float* ws = (float*)d_ws;
  const size_t M = 1u << 20;
  float* mln = ws;
  float* q = ws + 1 * M;
  float* k = ws + 2 * M;
  float* v = ws + 3 * M;
  float* g = ws + 4 * M;
  float* o = ws + 5 * M;
  bf16_t* bias = (bf16_t*)(ws + 6 * M);  // 33.5M bf16 = 64 MiB

  hipLaunchKernelGGL(ln_m_kernel, dim3(B_ * N_), dim3(128), 0, stream, m, lnmw,
                     lnmb, mln);
  hipLaunchKernelGGL(gemm512, dim3(8, 32, 4), dim3(256), 0, stream, mln,
                     (const float*)nullptr, wq, wk, wvv, wg, bg, bo, q, k, v, g,
                     -1);
  hipLaunchKernelGGL(zbias_kernel, dim3(N_, B_), dim3(256), 0, stream, z, lnzw,
                     lnzb, wz, bias);
  hipLaunchKernelGGL(attn_kernel, dim3(N_ / 8, H_, B_), dim3(256), 0, stream, q,
                     k, v, bias, mask, o);
  hipLaunchKernelGGL(gemm512, dim3(8, 32, 1), dim3(256), 0, stream, o, g, wo,
                     wo, wo, wo, bg, bo, out, out, out, out, 4);
}